// Round 1
// baseline (11152.556 us; speedup 1.0000x reference)
//
#include <hip/hip_runtime.h>
#include <stdint.h>

// Problem constants (setup_inputs is fixed)
#define HH 192
#define WW 192
#define BB 8
#define NCH 16          // state channels == hidden channels == 16
#define NSTEP 10
#define HWSZ (HH*WW)    // 36864
#define NPIX (BB*HWSZ)  // 294912
#define TILE 16
#define HALO 3
#define XT (TILE + 2*HALO)  // 22

// ---------------- Threefry-2x32 (exact JAX semantics) ----------------
__host__ __device__ inline void tf2x32(uint32_t k0, uint32_t k1,
                                       uint32_t x0, uint32_t x1,
                                       uint32_t &o0, uint32_t &o1) {
  const uint32_t k2 = k0 ^ k1 ^ 0x1BD11BDAu;
  x0 += k0; x1 += k1;
#define TFR(r) { x0 += x1; x1 = (x1 << (r)) | (x1 >> (32 - (r))); x1 ^= x0; }
  TFR(13) TFR(15) TFR(26) TFR(6)
  x0 += k1; x1 += k2 + 1u;
  TFR(17) TFR(29) TFR(16) TFR(24)
  x0 += k2; x1 += k0 + 2u;
  TFR(13) TFR(15) TFR(26) TFR(6)
  x0 += k0; x1 += k1 + 3u;
  TFR(17) TFR(29) TFR(16) TFR(24)
  x0 += k1; x1 += k2 + 4u;
  TFR(13) TFR(15) TFR(26) TFR(6)
  x0 += k2; x1 += k0 + 5u;
#undef TFR
  o0 = x0; o1 = x1;
}

// ------------- K0a: build rotated conv1 weights wlin[ci][ky][kx][co*4+r] -------------
__global__ void k_prep_w1(const float* __restrict__ w1, float* __restrict__ wlin) {
  int idx = blockIdx.x * 256 + threadIdx.x;   // total 16*49*64 = 50176
  if (idx >= 16 * 49 * 64) return;
  int j  = idx & 63;         // co*4 + r
  int t  = idx >> 6;         // ci*49 + ky*7 + kx
  int ci = t / 49;
  int rem = t - ci * 49;
  int ky = rem / 7, kx = rem - (rem / 7) * 7;
  int co = j >> 2, r = j & 3;
  // rot90 applied r times: R(W)[a,b] = W[b, K-1-a]
  int a = ky, b = kx;
  for (int i = 0; i < r; ++i) { int na = b, nb = 6 - a; a = na; b = nb; }
  wlin[idx] = w1[((co * 16 + ci) * 7 + a) * 7 + b];
}

// ------------- K0b: wsum[o][ci] = 0.25 * sum_t w2[o,ci,t] -------------
__global__ void k_prep_w2(const float* __restrict__ w2, float* __restrict__ wsum) {
  int idx = threadIdx.x;  // 256 = o*16 + ci
  int o = idx >> 4, ci = idx & 15;
  float s = 0.f;
  for (int t = 0; t < 4; ++t) s += w2[(o * 16 + ci) * 4 + t];
  wsum[idx] = 0.25f * s;
}

// ------------- K1: 7x7 P4 lifting conv (fp32) + BN block partials -------------
// y layout: [pixel][co*4+r]  (64 contiguous floats per pixel)
__global__ __launch_bounds__(256) void k_conv1(
    const float* __restrict__ xsrc,   // NHWC [B,H,W,16]
    const float* __restrict__ wlin,   // [16][7][7][64]
    const float* __restrict__ b1,     // [16]
    float* __restrict__ y,            // [NPIX][64]
    float* __restrict__ partials)     // [1152][32]
{
  __shared__ float xt[16][XT * XT];
  __shared__ float red[4][32];
  const int tid = threadIdx.x;
  const int tx = tid & 15, ty = tid >> 4;
  const int x0 = blockIdx.x * TILE, y0 = blockIdx.y * TILE;
  const int b = blockIdx.z;

  // stage x tile (+halo, zero padded) into LDS, NHWC -> [c][pix] transpose
  for (int p = tid; p < XT * XT; p += 256) {
    const int yy = p / XT, xx = p - yy * XT;
    const int gy = y0 + yy - HALO, gx = x0 + xx - HALO;
    float4 v0, v1, v2, v3;
    if ((unsigned)gy < (unsigned)HH && (unsigned)gx < (unsigned)WW) {
      const float4* px = (const float4*)(xsrc + ((size_t)b * HWSZ + (size_t)gy * WW + gx) * 16);
      v0 = px[0]; v1 = px[1]; v2 = px[2]; v3 = px[3];
    } else {
      v0 = v1 = v2 = v3 = make_float4(0.f, 0.f, 0.f, 0.f);
    }
    xt[0][p] = v0.x;  xt[1][p] = v0.y;  xt[2][p] = v0.z;  xt[3][p] = v0.w;
    xt[4][p] = v1.x;  xt[5][p] = v1.y;  xt[6][p] = v1.z;  xt[7][p] = v1.w;
    xt[8][p] = v2.x;  xt[9][p] = v2.y;  xt[10][p] = v2.z; xt[11][p] = v2.w;
    xt[12][p] = v3.x; xt[13][p] = v3.y; xt[14][p] = v3.z; xt[15][p] = v3.w;
  }
  __syncthreads();

  float acc[64];
#pragma unroll
  for (int j = 0; j < 64; ++j) acc[j] = b1[j >> 2];

  for (int ci = 0; ci < 16; ++ci) {
    for (int ky = 0; ky < 7; ++ky) {
      const float* xrow = &xt[ci][(ty + ky) * XT + tx];
      for (int kx = 0; kx < 7; ++kx) {
        const float xv = xrow[kx];
        const float* wp = wlin + (((ci * 7 + ky) * 7 + kx) << 6);  // block-uniform addr -> s_load
#pragma unroll
        for (int j = 0; j < 64; ++j) acc[j] = fmaf(xv, wp[j], acc[j]);
      }
    }
  }

  const size_t pix = (size_t)b * HWSZ + (size_t)(y0 + ty) * WW + (x0 + tx);
  float4* yp = (float4*)(y + pix * 64);
#pragma unroll
  for (int q = 0; q < 16; ++q)
    yp[q] = make_float4(acc[4 * q], acc[4 * q + 1], acc[4 * q + 2], acc[4 * q + 3]);

  // BN partials: per channel c, sum over this thread's 4 rotations
  float ps[16], ps2[16];
#pragma unroll
  for (int c = 0; c < 16; ++c) {
    float s = 0.f, s2 = 0.f;
#pragma unroll
    for (int r = 0; r < 4; ++r) { float v = acc[4 * c + r]; s += v; s2 += v * v; }
    ps[c] = s; ps2[c] = s2;
  }
  const int lane = tid & 63, wid = tid >> 6;
#pragma unroll
  for (int c = 0; c < 16; ++c) {
    float s = ps[c], s2 = ps2[c];
    for (int off = 32; off > 0; off >>= 1) { s += __shfl_down(s, off); s2 += __shfl_down(s2, off); }
    if (lane == 0) { red[wid][2 * c] = s; red[wid][2 * c + 1] = s2; }
  }
  __syncthreads();
  if (tid < 32) {
    float v = red[0][tid] + red[1][tid] + red[2][tid] + red[3][tid];
    const int blk = (b * gridDim.y + blockIdx.y) * gridDim.x + blockIdx.x;
    partials[(size_t)blk * 32 + tid] = v;
  }
}

// ------------- K2: reduce BN partials -> scale/shift per channel -------------
__global__ __launch_bounds__(256) void k_bnstats(
    const float* __restrict__ partials,  // [1152][32]
    const float* __restrict__ gamma, const float* __restrict__ beta,
    float* __restrict__ stats)           // [16][2] = scale, shift
{
  const int c = blockIdx.x;      // 16 blocks
  const int tid = threadIdx.x;   // 256
  float s = 0.f, s2 = 0.f;
  for (int i = tid; i < 1152; i += 256) {
    s  += partials[(size_t)i * 32 + 2 * c];
    s2 += partials[(size_t)i * 32 + 2 * c + 1];
  }
  __shared__ float rs[256], rs2[256];
  rs[tid] = s; rs2[tid] = s2;
  __syncthreads();
  for (int off = 128; off > 0; off >>= 1) {
    if (tid < off) { rs[tid] += rs[tid + off]; rs2[tid] += rs2[tid + off]; }
    __syncthreads();
  }
  if (tid == 0) {
    const float N = (float)BB * 4.f * HH * WW;  // 1,179,648
    const float mu = rs[0] / N;
    const float var = rs2[0] / N - mu * mu;
    const float rstd = rsqrtf(var + 1e-5f);
    const float sc = gamma[c] * rstd;
    stats[2 * c]     = sc;
    stats[2 * c + 1] = beta[c] - mu * sc;
  }
}

// ------------- K3: BN+relu+orientation-sum+1x1 conv+mask+state update -------------
__global__ __launch_bounds__(256) void k_update(
    const float* __restrict__ xsrc,  // NHWC state (d_in step0, else d_out)
    const float* __restrict__ y,     // [NPIX][64]
    const float* __restrict__ stats, // [16][2]
    const float* __restrict__ wsum,  // [16][16]
    const float* __restrict__ b2,    // [16]
    float* __restrict__ xdst,        // NHWC state out (d_out)
    uint32_t fk0, uint32_t fk1)
{
  __shared__ float sss[32];
  __shared__ float sws[256];
  __shared__ float sb2[16];
  const int tid = threadIdx.x;
  sws[tid] = wsum[tid];
  if (tid < 32) sss[tid] = stats[tid];
  if (tid < 16) sb2[tid] = b2[tid];
  __syncthreads();

  const size_t pix = (size_t)blockIdx.x * 256 + tid;  // < NPIX exactly
  const float4* yp = (const float4*)(y + pix * 64);
  float ysum[16];
#pragma unroll
  for (int c = 0; c < 16; ++c) {
    const float4 v = yp[c];
    const float sc = sss[2 * c], sh = sss[2 * c + 1];
    ysum[c] = fmaxf(fmaf(sc, v.x, sh), 0.f) + fmaxf(fmaf(sc, v.y, sh), 0.f)
            + fmaxf(fmaf(sc, v.z, sh), 0.f) + fmaxf(fmaf(sc, v.w, sh), 0.f);
  }

  // JAX partitionable threefry: bits = h0 ^ h1 of hash(fk, (0, i))
  uint32_t h0, h1;
  tf2x32(fk0, fk1, 0u, (uint32_t)pix, h0, h1);
  const uint32_t bits = h0 ^ h1;
  const float u = __uint_as_float((bits >> 9) | 0x3f800000u) - 1.0f;
  const float m = (u > 0.5f) ? 1.0f : 0.0f;

  const float4* xp = (const float4*)(xsrc + pix * 16);
  float4* op = (float4*)(xdst + pix * 16);
#pragma unroll
  for (int q = 0; q < 4; ++q) {
    const float4 xv = xp[q];
    float d[4];
#pragma unroll
    for (int jj = 0; jj < 4; ++jj) {
      const int o = 4 * q + jj;
      float s = sb2[o];
#pragma unroll
      for (int c = 0; c < 16; ++c) s = fmaf(sws[o * 16 + c], ysum[c], s);
      d[jj] = s;
    }
    float4 r;
    r.x = xv.x + d[0] * m;
    r.y = xv.y + d[1] * m;
    r.z = xv.z + d[2] * m;
    r.w = xv.w + d[3] * m;
    if (q == 0) r.x = xv.x;  // channel 0 clamped to original input
    op[q] = r;
  }
}

extern "C" void kernel_launch(void* const* d_in, const int* in_sizes, int n_in,
                              void* d_out, int out_size, void* d_ws, size_t ws_size,
                              hipStream_t stream) {
  const float* x_in  = (const float*)d_in[0];
  const float* w1    = (const float*)d_in[1];
  const float* b1    = (const float*)d_in[2];
  const float* gamma = (const float*)d_in[3];
  const float* beta  = (const float*)d_in[4];
  const float* w2    = (const float*)d_in[5];
  const float* b2    = (const float*)d_in[6];
  float* out = (float*)d_out;

  // workspace carve-up (floats): total ~75.8 MB
  float* ws       = (float*)d_ws;
  float* y        = ws;                              // NPIX*64 = 18,874,368
  float* wlin     = y + (size_t)NPIX * 64;           // 50,176
  float* wsum     = wlin + 16 * 49 * 64;             // 256
  float* partials = wsum + 256;                      // 1152*32 = 36,864
  float* stats    = partials + 1152 * 32;            // 32

  k_prep_w1<<<196, 256, 0, stream>>>(w1, wlin);
  k_prep_w2<<<1, 256, 0, stream>>>(w2, wsum);

  for (int s = 0; s < NSTEP; ++s) {
    const float* xs = (s == 0) ? x_in : out;
    k_conv1<<<dim3(WW / TILE, HH / TILE, BB), 256, 0, stream>>>(xs, wlin, b1, y, partials);
    k_bnstats<<<16, 256, 0, stream>>>(partials, gamma, beta, stats);
    // fold_in(key(42), s) on host (pure arithmetic)
    uint32_t fk0, fk1;
    tf2x32(0u, 42u, 0u, (uint32_t)s, fk0, fk1);
    k_update<<<NPIX / 256, 256, 0, stream>>>(xs, y, stats, wsum, b2, out, fk0, fk1);
  }
}

// Round 2
// 7232.738 us; speedup vs baseline: 1.5420x; 1.5420x over previous
//
#include <hip/hip_runtime.h>
#include <stdint.h>

// Problem constants (setup_inputs is fixed)
#define HH 192
#define WW 192
#define BB 8
#define NSTEP 10
#define HWSZ (HH*WW)    // 36864
#define NPIX (BB*HWSZ)  // 294912
#define TILE 16
#define HALO 3
#define XT 22           // TILE + 2*HALO
#define XSTRIDE 24      // padded row stride (bank-conflict-free)
#define WCH 4096        // padded floats per ci weight chunk (3136 used)

typedef __attribute__((address_space(1))) const uint32_t glb_u32;
typedef __attribute__((address_space(3))) uint32_t lds_u32;

// ---------------- Threefry-2x32 (exact JAX semantics) ----------------
__host__ __device__ inline void tf2x32(uint32_t k0, uint32_t k1,
                                       uint32_t x0, uint32_t x1,
                                       uint32_t &o0, uint32_t &o1) {
  const uint32_t k2 = k0 ^ k1 ^ 0x1BD11BDAu;
  x0 += k0; x1 += k1;
#define TFR(r) { x0 += x1; x1 = (x1 << (r)) | (x1 >> (32 - (r))); x1 ^= x0; }
  TFR(13) TFR(15) TFR(26) TFR(6)
  x0 += k1; x1 += k2 + 1u;
  TFR(17) TFR(29) TFR(16) TFR(24)
  x0 += k2; x1 += k0 + 2u;
  TFR(13) TFR(15) TFR(26) TFR(6)
  x0 += k0; x1 += k1 + 3u;
  TFR(17) TFR(29) TFR(16) TFR(24)
  x0 += k1; x1 += k2 + 4u;
  TFR(13) TFR(15) TFR(26) TFR(6)
  x0 += k2; x1 += k0 + 5u;
#undef TFR
  o0 = x0; o1 = x1;
}

// ------------- K0a: build rotated conv1 weights wlin[ci][(ky*7+kx)*64 + co*4+r] -------------
__global__ void k_prep_w1(const float* __restrict__ w1, float* __restrict__ wlin) {
  int idx = blockIdx.x * 256 + threadIdx.x;   // total 16*49*64 = 50176
  if (idx >= 16 * 49 * 64) return;
  int j  = idx & 63;         // co*4 + r
  int t  = idx >> 6;         // ci*49 + ky*7 + kx
  int ci = t / 49;
  int rem = t - ci * 49;
  int ky = rem / 7, kx = rem - (rem / 7) * 7;
  int r = j & 3, co = j >> 2;
  // rot90 applied r times: R(W)[a,b] = W[b, K-1-a]
  int a = ky, b = kx;
  for (int i = 0; i < r; ++i) { int na = b, nb = 6 - a; a = na; b = nb; }
  wlin[(size_t)ci * WCH + rem * 64 + j] = w1[((co * 16 + ci) * 7 + a) * 7 + b];
}

// ------------- K0b: wsum[o][ci] = 0.25 * sum_t w2[o,ci,t] -------------
__global__ void k_prep_w2(const float* __restrict__ w2, float* __restrict__ wsum) {
  int idx = threadIdx.x;  // 256 = o*16 + ci
  float s = 0.f;
  for (int t = 0; t < 4; ++t) s += w2[idx * 4 + t];
  wsum[idx] = 0.25f * s;
}

// ------------- K1: 7x7 P4 lifting conv (fp32) + BN block partials -------------
// Weights staged per-ci into LDS (double-buffered, global_load_lds width=16).
// Inner loop: only ds_read (broadcast weights + x tile) + v_fma. No s_loads.
__global__ __launch_bounds__(256) void k_conv1(
    const float* __restrict__ xsrc,   // NHWC [B,H,W,16]
    const float* __restrict__ wlin,   // [16][WCH]
    const float* __restrict__ b1,     // [16]
    float* __restrict__ y,            // [NPIX][64]
    float* __restrict__ partials)     // [1152][32]
{
  __shared__ float xt[16][XT * XSTRIDE];   // 33792 B
  __shared__ float wbuf[2][WCH];           // 32768 B
  __shared__ float red[4][32];
  const int tid = threadIdx.x;
  const int tx = tid & 15, ty = tid >> 4;
  const int x0 = blockIdx.x * TILE, y0 = blockIdx.y * TILE;
  const int b = blockIdx.z;

  // stage x tile (+halo, zero padded) into LDS, NHWC -> [c][row][col] transpose
  for (int p = tid; p < XT * XT; p += 256) {
    const int yy = p / XT, xx = p - yy * XT;
    const int gy = y0 + yy - HALO, gx = x0 + xx - HALO;
    float4 v0, v1, v2, v3;
    if ((unsigned)gy < (unsigned)HH && (unsigned)gx < (unsigned)WW) {
      const float4* px = (const float4*)(xsrc + ((size_t)b * HWSZ + (size_t)gy * WW + gx) * 16);
      v0 = px[0]; v1 = px[1]; v2 = px[2]; v3 = px[3];
    } else {
      v0 = v1 = v2 = v3 = make_float4(0.f, 0.f, 0.f, 0.f);
    }
    const int q = yy * XSTRIDE + xx;
    xt[0][q] = v0.x;  xt[1][q] = v0.y;  xt[2][q] = v0.z;  xt[3][q] = v0.w;
    xt[4][q] = v1.x;  xt[5][q] = v1.y;  xt[6][q] = v1.z;  xt[7][q] = v1.w;
    xt[8][q] = v2.x;  xt[9][q] = v2.y;  xt[10][q] = v2.z; xt[11][q] = v2.w;
    xt[12][q] = v3.x; xt[13][q] = v3.y; xt[14][q] = v3.z; xt[15][q] = v3.w;
  }

  // async weight stage: chunk ci -> wbuf[buf]; lane l of wave w writes
  // floats [w*256 + l*4 .. +3] of round r at LDS base + r*1024 (linear order).
  auto stage_w = [&](int buf, int ci) {
    const float* g = wlin + (size_t)ci * WCH + (tid << 2);
    float* l = &wbuf[buf][(tid & ~63) << 2];
#pragma unroll
    for (int r2 = 0; r2 < 4; ++r2)
      __builtin_amdgcn_global_load_lds((glb_u32*)(g + r2 * 1024),
                                       (lds_u32*)(l + r2 * 1024), 16, 0, 0);
  };

  stage_w(0, 0);
  __syncthreads();   // drains vmcnt (wbuf[0] ready) + x tile visible

  float acc[64];
#pragma unroll
  for (int j = 0; j < 64; ++j) acc[j] = b1[j >> 2];

  for (int ci = 0; ci < 16; ++ci) {
    if (ci < 15) stage_w((ci + 1) & 1, ci + 1);
    const float* wb = wbuf[ci & 1];
    const float* xr0 = &xt[ci][ty * XSTRIDE + tx];
#pragma unroll 1
    for (int ky = 0; ky < 7; ++ky) {
      const float* xr = xr0 + ky * XSTRIDE;
#pragma unroll
      for (int kx = 0; kx < 7; ++kx) {
        const float xv = xr[kx];
        const float* wp = wb + ((ky * 7 + kx) << 6);  // uniform -> broadcast ds_read_b128
#pragma unroll
        for (int j = 0; j < 64; ++j) acc[j] = fmaf(xv, wp[j], acc[j]);
      }
    }
    __syncthreads();  // compiler emits vmcnt(0)+lgkmcnt(0) drain: next wbuf ready, cur safe to overwrite
  }

  const size_t pix = (size_t)b * HWSZ + (size_t)(y0 + ty) * WW + (x0 + tx);
  float4* yp = (float4*)(y + pix * 64);
#pragma unroll
  for (int q = 0; q < 16; ++q)
    yp[q] = make_float4(acc[4 * q], acc[4 * q + 1], acc[4 * q + 2], acc[4 * q + 3]);

  // BN partials: per channel c, sum over this thread's 4 rotations
  float ps[16], ps2[16];
#pragma unroll
  for (int c = 0; c < 16; ++c) {
    float s = 0.f, s2 = 0.f;
#pragma unroll
    for (int r = 0; r < 4; ++r) { float v = acc[4 * c + r]; s += v; s2 += v * v; }
    ps[c] = s; ps2[c] = s2;
  }
  const int lane = tid & 63, wid = tid >> 6;
#pragma unroll
  for (int c = 0; c < 16; ++c) {
    float s = ps[c], s2 = ps2[c];
    for (int off = 32; off > 0; off >>= 1) { s += __shfl_down(s, off); s2 += __shfl_down(s2, off); }
    if (lane == 0) { red[wid][2 * c] = s; red[wid][2 * c + 1] = s2; }
  }
  __syncthreads();
  if (tid < 32) {
    float v = red[0][tid] + red[1][tid] + red[2][tid] + red[3][tid];
    const int blk = (b * gridDim.y + blockIdx.y) * gridDim.x + blockIdx.x;
    partials[(size_t)blk * 32 + tid] = v;
  }
}

// ------------- K2: reduce BN partials -> scale/shift per channel -------------
__global__ __launch_bounds__(256) void k_bnstats(
    const float* __restrict__ partials,  // [1152][32]
    const float* __restrict__ gamma, const float* __restrict__ beta,
    float* __restrict__ stats)           // [16][2] = scale, shift
{
  const int c = blockIdx.x;      // 16 blocks
  const int tid = threadIdx.x;   // 256
  float s = 0.f, s2 = 0.f;
  for (int i = tid; i < 1152; i += 256) {
    s  += partials[(size_t)i * 32 + 2 * c];
    s2 += partials[(size_t)i * 32 + 2 * c + 1];
  }
  __shared__ float rs[256], rs2[256];
  rs[tid] = s; rs2[tid] = s2;
  __syncthreads();
  for (int off = 128; off > 0; off >>= 1) {
    if (tid < off) { rs[tid] += rs[tid + off]; rs2[tid] += rs2[tid + off]; }
    __syncthreads();
  }
  if (tid == 0) {
    const float N = (float)BB * 4.f * HH * WW;  // 1,179,648
    const float mu = rs[0] / N;
    const float var = rs2[0] / N - mu * mu;
    const float rstd = rsqrtf(var + 1e-5f);
    const float sc = gamma[c] * rstd;
    stats[2 * c]     = sc;
    stats[2 * c + 1] = beta[c] - mu * sc;
  }
}

// ------------- K3: BN+relu+orientation-sum+1x1 conv+mask+state update -------------
__global__ __launch_bounds__(256) void k_update(
    const float* __restrict__ xsrc,  // NHWC state (d_in step0, else d_out)
    const float* __restrict__ y,     // [NPIX][64]
    const float* __restrict__ stats, // [16][2]
    const float* __restrict__ wsum,  // [16][16]
    const float* __restrict__ b2,    // [16]
    float* __restrict__ xdst,        // NHWC state out (d_out)
    uint32_t fk0, uint32_t fk1)
{
  __shared__ float sss[32];
  __shared__ float sws[256];
  __shared__ float sb2[16];
  const int tid = threadIdx.x;
  sws[tid] = wsum[tid];
  if (tid < 32) sss[tid] = stats[tid];
  if (tid < 16) sb2[tid] = b2[tid];
  __syncthreads();

  const size_t pix = (size_t)blockIdx.x * 256 + tid;  // < NPIX exactly
  const float4* yp = (const float4*)(y + pix * 64);
  float ysum[16];
#pragma unroll
  for (int c = 0; c < 16; ++c) {
    const float4 v = yp[c];
    const float sc = sss[2 * c], sh = sss[2 * c + 1];
    ysum[c] = fmaxf(fmaf(sc, v.x, sh), 0.f) + fmaxf(fmaf(sc, v.y, sh), 0.f)
            + fmaxf(fmaf(sc, v.z, sh), 0.f) + fmaxf(fmaf(sc, v.w, sh), 0.f);
  }

  // JAX partitionable threefry: bits = h0 ^ h1 of hash(fk, (0, i))
  uint32_t h0, h1;
  tf2x32(fk0, fk1, 0u, (uint32_t)pix, h0, h1);
  const uint32_t bits = h0 ^ h1;
  const float u = __uint_as_float((bits >> 9) | 0x3f800000u) - 1.0f;
  const float m = (u > 0.5f) ? 1.0f : 0.0f;

  const float4* xp = (const float4*)(xsrc + pix * 16);
  float4* op = (float4*)(xdst + pix * 16);
#pragma unroll
  for (int q = 0; q < 4; ++q) {
    const float4 xv = xp[q];
    float d[4];
#pragma unroll
    for (int jj = 0; jj < 4; ++jj) {
      const int o = 4 * q + jj;
      float s = sb2[o];
#pragma unroll
      for (int c = 0; c < 16; ++c) s = fmaf(sws[o * 16 + c], ysum[c], s);
      d[jj] = s;
    }
    float4 r;
    r.x = xv.x + d[0] * m;
    r.y = xv.y + d[1] * m;
    r.z = xv.z + d[2] * m;
    r.w = xv.w + d[3] * m;
    if (q == 0) r.x = xv.x;  // channel 0 clamped to original input
    op[q] = r;
  }
}

extern "C" void kernel_launch(void* const* d_in, const int* in_sizes, int n_in,
                              void* d_out, int out_size, void* d_ws, size_t ws_size,
                              hipStream_t stream) {
  const float* x_in  = (const float*)d_in[0];
  const float* w1    = (const float*)d_in[1];
  const float* b1    = (const float*)d_in[2];
  const float* gamma = (const float*)d_in[3];
  const float* beta  = (const float*)d_in[4];
  const float* w2    = (const float*)d_in[5];
  const float* b2    = (const float*)d_in[6];
  float* out = (float*)d_out;

  // workspace carve-up (floats): total ~75.9 MB
  float* ws       = (float*)d_ws;
  float* y        = ws;                              // NPIX*64 = 18,874,368
  float* wlin     = y + (size_t)NPIX * 64;           // 16*WCH = 65,536
  float* wsum     = wlin + 16 * WCH;                 // 256
  float* partials = wsum + 256;                      // 1152*32 = 36,864
  float* stats    = partials + 1152 * 32;            // 32

  k_prep_w1<<<196, 256, 0, stream>>>(w1, wlin);
  k_prep_w2<<<1, 256, 0, stream>>>(w2, wsum);

  for (int s = 0; s < NSTEP; ++s) {
    const float* xs = (s == 0) ? x_in : out;
    k_conv1<<<dim3(WW / TILE, HH / TILE, BB), 256, 0, stream>>>(xs, wlin, b1, y, partials);
    k_bnstats<<<16, 256, 0, stream>>>(partials, gamma, beta, stats);
    // fold_in(key(42), s) on host (pure arithmetic)
    uint32_t fk0, fk1;
    tf2x32(0u, 42u, 0u, (uint32_t)s, fk0, fk1);
    k_update<<<NPIX / 256, 256, 0, stream>>>(xs, y, stats, wsum, b2, out, fk0, fk1);
  }
}

// Round 3
// 3512.773 us; speedup vs baseline: 3.1749x; 2.0590x over previous
//
#include <hip/hip_runtime.h>
#include <stdint.h>

// Problem constants (setup_inputs is fixed)
#define HH 192
#define WW 192
#define BB 8
#define NSTEP 10
#define HWSZ (HH*WW)    // 36864
#define NPIX (BB*HWSZ)  // 294912
#define TILE 16
#define HALO 3
#define XT 22           // TILE + 2*HALO
#define XSTRIDE 24      // padded row stride (16B-aligned strips, ≤2-way banks)
#define WCH 4096        // padded floats per ci weight chunk (3136 used)

typedef __attribute__((address_space(1))) const uint32_t glb_u32;
typedef __attribute__((address_space(3))) uint32_t lds_u32;

// ---------------- Threefry-2x32 (exact JAX semantics) ----------------
__host__ __device__ inline void tf2x32(uint32_t k0, uint32_t k1,
                                       uint32_t x0, uint32_t x1,
                                       uint32_t &o0, uint32_t &o1) {
  const uint32_t k2 = k0 ^ k1 ^ 0x1BD11BDAu;
  x0 += k0; x1 += k1;
#define TFR(r) { x0 += x1; x1 = (x1 << (r)) | (x1 >> (32 - (r))); x1 ^= x0; }
  TFR(13) TFR(15) TFR(26) TFR(6)
  x0 += k1; x1 += k2 + 1u;
  TFR(17) TFR(29) TFR(16) TFR(24)
  x0 += k2; x1 += k0 + 2u;
  TFR(13) TFR(15) TFR(26) TFR(6)
  x0 += k0; x1 += k1 + 3u;
  TFR(17) TFR(29) TFR(16) TFR(24)
  x0 += k1; x1 += k2 + 4u;
  TFR(13) TFR(15) TFR(26) TFR(6)
  x0 += k2; x1 += k0 + 5u;
#undef TFR
  o0 = x0; o1 = x1;
}

// ------------- K0a: build rotated conv1 weights wlin[ci][(ky*7+kx)*64 + co*4+r] -------------
__global__ void k_prep_w1(const float* __restrict__ w1, float* __restrict__ wlin) {
  int idx = blockIdx.x * 256 + threadIdx.x;   // total 16*49*64 = 50176
  if (idx >= 16 * 49 * 64) return;
  int j  = idx & 63;         // co*4 + r
  int t  = idx >> 6;         // ci*49 + ky*7 + kx
  int ci = t / 49;
  int rem = t - ci * 49;
  int r = j & 3, co = j >> 2;
  int ky = rem / 7, kx = rem - (rem / 7) * 7;
  // rot90 applied r times: R(W)[a,b] = W[b, K-1-a]
  int a = ky, b = kx;
  for (int i = 0; i < r; ++i) { int na = b, nb = 6 - a; a = na; b = nb; }
  wlin[(size_t)ci * WCH + rem * 64 + j] = w1[((co * 16 + ci) * 7 + a) * 7 + b];
}

// ------------- K0b: wsum[o][ci] = 0.25 * sum_t w2[o,ci,t] -------------
__global__ void k_prep_w2(const float* __restrict__ w2, float* __restrict__ wsum) {
  int idx = threadIdx.x;  // 256 = o*16 + ci
  float s = 0.f;
  for (int t = 0; t < 4; ++t) s += w2[idx * 4 + t];
  wsum[idx] = 0.25f * s;
}

// ------------- K1: 7x7 P4 lifting conv (fp32), register-tiled 8px x 8j -------------
// Thread (jg = tid&7, pg = tid>>3): outputs j = jg*8..jg*8+7 for 8 pixels
// (row = pg>>1, cols (pg&1)*8 .. +7). Per tap: 2 ds_read_b128 weights reused
// over 8 pixels; per ky: 4 ds_read_b128 x sliding window reused over 7 kx.
__global__ __launch_bounds__(256) void k_conv1(
    const float* __restrict__ xsrc,   // NHWC [B,H,W,16]
    const float* __restrict__ wlin,   // [16][WCH]
    const float* __restrict__ b1,     // [16]
    float* __restrict__ y,            // [NPIX][64]
    float* __restrict__ partials)     // [1152][32]
{
  __shared__ float xt[16][XT * XSTRIDE];   // 33792 B
  __shared__ float wbuf[2][WCH];           // 32768 B
  __shared__ float red[4][32];
  const int tid = threadIdx.x;
  const int jg = tid & 7;          // output group: j = jg*8 + jj
  const int pg = tid >> 3;         // pixel group 0..31
  const int prow = pg >> 1;        // 0..15
  const int pcol = (pg & 1) << 3;  // 0 or 8
  const int x0 = blockIdx.x * TILE, y0 = blockIdx.y * TILE;
  const int b = blockIdx.z;

  // stage x tile (+halo, zero padded) into LDS, NHWC -> [c][row][col] transpose
  for (int p = tid; p < XT * XT; p += 256) {
    const int yy = p / XT, xx = p - yy * XT;
    const int gy = y0 + yy - HALO, gx = x0 + xx - HALO;
    float4 v0, v1, v2, v3;
    if ((unsigned)gy < (unsigned)HH && (unsigned)gx < (unsigned)WW) {
      const float4* px = (const float4*)(xsrc + ((size_t)b * HWSZ + (size_t)gy * WW + gx) * 16);
      v0 = px[0]; v1 = px[1]; v2 = px[2]; v3 = px[3];
    } else {
      v0 = v1 = v2 = v3 = make_float4(0.f, 0.f, 0.f, 0.f);
    }
    const int q = yy * XSTRIDE + xx;
    xt[0][q] = v0.x;  xt[1][q] = v0.y;  xt[2][q] = v0.z;  xt[3][q] = v0.w;
    xt[4][q] = v1.x;  xt[5][q] = v1.y;  xt[6][q] = v1.z;  xt[7][q] = v1.w;
    xt[8][q] = v2.x;  xt[9][q] = v2.y;  xt[10][q] = v2.z; xt[11][q] = v2.w;
    xt[12][q] = v3.x; xt[13][q] = v3.y; xt[14][q] = v3.z; xt[15][q] = v3.w;
  }

  // async weight stage: chunk ci -> wbuf[buf] (linear lane order, width=16)
  auto stage_w = [&](int buf, int ci) {
    const float* g = wlin + (size_t)ci * WCH + (tid << 2);
    float* l = &wbuf[buf][(tid & ~63) << 2];
#pragma unroll
    for (int r2 = 0; r2 < 4; ++r2)
      __builtin_amdgcn_global_load_lds((glb_u32*)(g + r2 * 1024),
                                       (lds_u32*)(l + r2 * 1024), 16, 0, 0);
  };

  stage_w(0, 0);
  __syncthreads();   // drains vmcnt (wbuf[0] ready) + x tile visible

  const float bv0 = b1[jg >> 1];       // j = jg*8+jj -> channel = jg*2 + (jj>>2)
  const float bv1 = b1[(jg << 1) + 1 >> 0 == 0 ? 0 : (jg * 2 + 1)];  // (kept simple below)
  float acc[8][8];
#pragma unroll
  for (int p = 0; p < 8; ++p) {
#pragma unroll
    for (int jj = 0; jj < 8; ++jj) acc[p][jj] = 0.f;
  }

#pragma unroll 1
  for (int ci = 0; ci < 16; ++ci) {
    if (ci < 15) stage_w((ci + 1) & 1, ci + 1);
    const float* wb = wbuf[ci & 1] + (jg << 3);
    const float* xb = &xt[ci][prow * XSTRIDE + pcol];
#pragma unroll 1
    for (int ky = 0; ky < 7; ++ky) {
      const float* xr = xb + ky * XSTRIDE;
      const float4 xa = *(const float4*)(xr);
      const float4 xbv = *(const float4*)(xr + 4);
      const float4 xc = *(const float4*)(xr + 8);
      const float4 xd = *(const float4*)(xr + 12);
      const float xw[16] = {xa.x, xa.y, xa.z, xa.w, xbv.x, xbv.y, xbv.z, xbv.w,
                            xc.x, xc.y, xc.z, xc.w, xd.x, xd.y, xd.z, xd.w};
#pragma unroll
      for (int kx = 0; kx < 7; ++kx) {
        const float* wp = wb + ((ky * 7 + kx) << 6);
        const float4 w0 = *(const float4*)(wp);
        const float4 w1v = *(const float4*)(wp + 4);
        const float w[8] = {w0.x, w0.y, w0.z, w0.w, w1v.x, w1v.y, w1v.z, w1v.w};
#pragma unroll
        for (int p = 0; p < 8; ++p) {
          const float xv = xw[p + kx];
#pragma unroll
          for (int jj = 0; jj < 8; ++jj) acc[p][jj] = fmaf(xv, w[jj], acc[p][jj]);
        }
      }
    }
    __syncthreads();  // vmcnt+lgkm drain: next wbuf ready, cur safe to overwrite
  }

  // add bias (j = jg*8 + jj -> channel jg*2 + (jj>>2))
  const float bc0 = b1[jg * 2], bc1 = b1[jg * 2 + 1];
#pragma unroll
  for (int p = 0; p < 8; ++p) {
#pragma unroll
    for (int jj = 0; jj < 8; ++jj) acc[p][jj] += (jj < 4) ? bc0 : bc1;
  }

  // write y: pixel (b, y0+prow, x0+pcol+p), channels jg*8..jg*8+7
  const size_t pixbase = (size_t)b * HWSZ + (size_t)(y0 + prow) * WW + (x0 + pcol);
#pragma unroll
  for (int p = 0; p < 8; ++p) {
    float4* yp = (float4*)(y + (pixbase + p) * 64 + jg * 8);
    yp[0] = make_float4(acc[p][0], acc[p][1], acc[p][2], acc[p][3]);
    yp[1] = make_float4(acc[p][4], acc[p][5], acc[p][6], acc[p][7]);
  }

  // BN partials: thread covers channels c0=jg*2 (jj 0..3) and c1=jg*2+1 (jj 4..7)
  float s0 = 0.f, q0 = 0.f, s1 = 0.f, q1 = 0.f;
#pragma unroll
  for (int p = 0; p < 8; ++p) {
#pragma unroll
    for (int r = 0; r < 4; ++r) {
      const float v0 = acc[p][r], v1 = acc[p][4 + r];
      s0 += v0; q0 += v0 * v0;
      s1 += v1; q1 += v1 * v1;
    }
  }
  const int lane = tid & 63, wid = tid >> 6;
#pragma unroll
  for (int off = 32; off >= 8; off >>= 1) {
    s0 += __shfl_down(s0, off); q0 += __shfl_down(q0, off);
    s1 += __shfl_down(s1, off); q1 += __shfl_down(q1, off);
  }
  if (lane < 8) {   // lane == jg; channels 2*lane, 2*lane+1
    red[wid][lane * 4 + 0] = s0;
    red[wid][lane * 4 + 1] = q0;
    red[wid][lane * 4 + 2] = s1;
    red[wid][lane * 4 + 3] = q1;
  }
  __syncthreads();
  if (tid < 32) {
    float v = red[0][tid] + red[1][tid] + red[2][tid] + red[3][tid];
    const int blk = (b * gridDim.y + blockIdx.y) * gridDim.x + blockIdx.x;
    partials[(size_t)blk * 32 + tid] = v;
  }
}

// ------------- K2: reduce BN partials -> scale/shift per channel -------------
__global__ __launch_bounds__(256) void k_bnstats(
    const float* __restrict__ partials,  // [1152][32]
    const float* __restrict__ gamma, const float* __restrict__ beta,
    float* __restrict__ stats)           // [16][2] = scale, shift
{
  const int c = blockIdx.x;      // 16 blocks
  const int tid = threadIdx.x;   // 256
  float s = 0.f, s2 = 0.f;
  for (int i = tid; i < 1152; i += 256) {
    s  += partials[(size_t)i * 32 + 2 * c];
    s2 += partials[(size_t)i * 32 + 2 * c + 1];
  }
  __shared__ float rs[256], rs2[256];
  rs[tid] = s; rs2[tid] = s2;
  __syncthreads();
  for (int off = 128; off > 0; off >>= 1) {
    if (tid < off) { rs[tid] += rs[tid + off]; rs2[tid] += rs2[tid + off]; }
    __syncthreads();
  }
  if (tid == 0) {
    const float N = (float)BB * 4.f * HH * WW;  // 1,179,648
    const float mu = rs[0] / N;
    const float var = rs2[0] / N - mu * mu;
    const float rstd = rsqrtf(var + 1e-5f);
    const float sc = gamma[c] * rstd;
    stats[2 * c]     = sc;
    stats[2 * c + 1] = beta[c] - mu * sc;
  }
}

// ------------- K3: BN+relu+orientation-sum+1x1 conv+mask+state update -------------
__global__ __launch_bounds__(256) void k_update(
    const float* __restrict__ xsrc,  // NHWC state (d_in step0, else d_out)
    const float* __restrict__ y,     // [NPIX][64]
    const float* __restrict__ stats, // [16][2]
    const float* __restrict__ wsum,  // [16][16]
    const float* __restrict__ b2,    // [16]
    float* __restrict__ xdst,        // NHWC state out (d_out)
    uint32_t fk0, uint32_t fk1)
{
  __shared__ float sss[32];
  __shared__ float sws[256];
  __shared__ float sb2[16];
  const int tid = threadIdx.x;
  sws[tid] = wsum[tid];
  if (tid < 32) sss[tid] = stats[tid];
  if (tid < 16) sb2[tid] = b2[tid];
  __syncthreads();

  const size_t pix = (size_t)blockIdx.x * 256 + tid;  // < NPIX exactly
  const float4* yp = (const float4*)(y + pix * 64);
  float ysum[16];
#pragma unroll
  for (int c = 0; c < 16; ++c) {
    const float4 v = yp[c];
    const float sc = sss[2 * c], sh = sss[2 * c + 1];
    ysum[c] = fmaxf(fmaf(sc, v.x, sh), 0.f) + fmaxf(fmaf(sc, v.y, sh), 0.f)
            + fmaxf(fmaf(sc, v.z, sh), 0.f) + fmaxf(fmaf(sc, v.w, sh), 0.f);
  }

  // JAX partitionable threefry: bits = h0 ^ h1 of hash(fk, (0, i))
  uint32_t h0, h1;
  tf2x32(fk0, fk1, 0u, (uint32_t)pix, h0, h1);
  const uint32_t bits = h0 ^ h1;
  const float u = __uint_as_float((bits >> 9) | 0x3f800000u) - 1.0f;
  const float m = (u > 0.5f) ? 1.0f : 0.0f;

  const float4* xp = (const float4*)(xsrc + pix * 16);
  float4* op = (float4*)(xdst + pix * 16);
#pragma unroll
  for (int q = 0; q < 4; ++q) {
    const float4 xv = xp[q];
    float d[4];
#pragma unroll
    for (int jj = 0; jj < 4; ++jj) {
      const int o = 4 * q + jj;
      float s = sb2[o];
#pragma unroll
      for (int c = 0; c < 16; ++c) s = fmaf(sws[o * 16 + c], ysum[c], s);
      d[jj] = s;
    }
    float4 r;
    r.x = xv.x + d[0] * m;
    r.y = xv.y + d[1] * m;
    r.z = xv.z + d[2] * m;
    r.w = xv.w + d[3] * m;
    if (q == 0) r.x = xv.x;  // channel 0 clamped to original input
    op[q] = r;
  }
}

extern "C" void kernel_launch(void* const* d_in, const int* in_sizes, int n_in,
                              void* d_out, int out_size, void* d_ws, size_t ws_size,
                              hipStream_t stream) {
  const float* x_in  = (const float*)d_in[0];
  const float* w1    = (const float*)d_in[1];
  const float* b1    = (const float*)d_in[2];
  const float* gamma = (const float*)d_in[3];
  const float* beta  = (const float*)d_in[4];
  const float* w2    = (const float*)d_in[5];
  const float* b2    = (const float*)d_in[6];
  float* out = (float*)d_out;

  // workspace carve-up (floats): total ~75.9 MB
  float* ws       = (float*)d_ws;
  float* y        = ws;                              // NPIX*64 = 18,874,368
  float* wlin     = y + (size_t)NPIX * 64;           // 16*WCH = 65,536
  float* wsum     = wlin + 16 * WCH;                 // 256
  float* partials = wsum + 256;                      // 1152*32 = 36,864
  float* stats    = partials + 1152 * 32;            // 32

  k_prep_w1<<<196, 256, 0, stream>>>(w1, wlin);
  k_prep_w2<<<1, 256, 0, stream>>>(w2, wsum);

  for (int s = 0; s < NSTEP; ++s) {
    const float* xs = (s == 0) ? x_in : out;
    k_conv1<<<dim3(WW / TILE, HH / TILE, BB), 256, 0, stream>>>(xs, wlin, b1, y, partials);
    k_bnstats<<<16, 256, 0, stream>>>(partials, gamma, beta, stats);
    // fold_in(key(42), s) on host (pure arithmetic)
    uint32_t fk0, fk1;
    tf2x32(0u, 42u, 0u, (uint32_t)s, fk0, fk1);
    k_update<<<NPIX / 256, 256, 0, stream>>>(xs, y, stats, wsum, b2, out, fk0, fk1);
  }
}

// Round 4
// 1789.344 us; speedup vs baseline: 6.2328x; 1.9632x over previous
//
#include <hip/hip_runtime.h>
#include <stdint.h>

// Problem constants (setup_inputs is fixed)
#define HH 192
#define WW 192
#define BB 8
#define NSTEP 10
#define HWSZ (HH*WW)    // 36864
#define NPIX (BB*HWSZ)  // 294912
#define TILE 16

// x LDS tile geometry (f16, pixel-major): rows 0..22 (22 real + 1 pad for tap-49),
// row stride 376 ushorts = 752 B = 47*16B -> per-lane row-strided b128 reads are 2-way banked (free)
#define XROWS 23
#define RSU   376                 // ushorts per row
#define XBUFU (XROWS*RSU)         // 8648 ushorts per buffer (hi); lo at +XBUFU
#define NKS   25                  // K-steps: K = 50 taps (49 + 1 zero-pad) * 16 ci / 32

typedef _Float16 f16x8 __attribute__((ext_vector_type(8)));
typedef float    f32x4 __attribute__((ext_vector_type(4)));

union PackU { ushort u[8]; uint4 v; };

// ---------------- Threefry-2x32 (exact JAX semantics) ----------------
__host__ __device__ inline void tf2x32(uint32_t k0, uint32_t k1,
                                       uint32_t x0, uint32_t x1,
                                       uint32_t &o0, uint32_t &o1) {
  const uint32_t k2 = k0 ^ k1 ^ 0x1BD11BDAu;
  x0 += k0; x1 += k1;
#define TFR(r) { x0 += x1; x1 = (x1 << (r)) | (x1 >> (32 - (r))); x1 ^= x0; }
  TFR(13) TFR(15) TFR(26) TFR(6)
  x0 += k1; x1 += k2 + 1u;
  TFR(17) TFR(29) TFR(16) TFR(24)
  x0 += k2; x1 += k0 + 2u;
  TFR(13) TFR(15) TFR(26) TFR(6)
  x0 += k0; x1 += k1 + 3u;
  TFR(17) TFR(29) TFR(16) TFR(24)
  x0 += k1; x1 += k2 + 4u;
  TFR(13) TFR(15) TFR(26) TFR(6)
  x0 += k2; x1 += k0 + 5u;
#undef TFR
  o0 = x0; o1 = x1;
}

__device__ inline void split2048(float v, ushort &h, ushort &l) {
  _Float16 hi = (_Float16)v;
  float r = (v - (float)hi) * 2048.0f;   // scale lo into normal f16 range
  _Float16 lo = (_Float16)r;
  h = __builtin_bit_cast(ushort, hi);
  l = __builtin_bit_cast(ushort, lo);
}

// ------------- K0a: weights -> A-fragment order, f16 hi/lo (lo scaled x2048) -------------
// frag index f = (s*4 + mt)*64 + lane ; lane: m = lane&15 -> j = mt*16+m; g = lane>>4;
// elems e: k = 32s + 8g + e -> tap t = 2s + (g>>1), ci = 8*(g&1) + e.
__global__ void k_prep_wfrag(const float* __restrict__ w1,
                             ushort* __restrict__ wfh, ushort* __restrict__ wfl) {
  int idx = blockIdx.x * 256 + threadIdx.x;   // 6400 total
  if (idx >= NKS * 4 * 64) return;
  const int lane = idx & 63;
  const int sm = idx >> 6;            // s*4 + mt
  const int s = sm >> 2, mt = sm & 3;
  const int m = lane & 15, g = lane >> 4;
  const int j = mt * 16 + m, co = j >> 2, r = j & 3;
  const int t = 2 * s + (g >> 1);
  PackU ph, pl;
#pragma unroll
  for (int e = 0; e < 8; ++e) {
    const int ci = 8 * (g & 1) + e;
    float wv = 0.f;
    if (t < 49) {
      const int ky = t / 7, kx = t - (t / 7) * 7;
      int a = ky, b = kx;
      for (int i = 0; i < r; ++i) { int na = b, nb = 6 - a; a = na; b = nb; }
      wv = w1[((co * 16 + ci) * 7 + a) * 7 + b];
    }
    split2048(wv, ph.u[e], pl.u[e]);
  }
  ((uint4*)wfh)[sm * 64 + lane] = ph.v;
  ((uint4*)wfl)[sm * 64 + lane] = pl.v;
}

// ------------- K0b: wsum[o][ci] = 0.25 * sum_t w2[o,ci,t] -------------
__global__ void k_prep_w2(const float* __restrict__ w2, float* __restrict__ wsum) {
  int idx = threadIdx.x;  // 256 = o*16 + ci
  float s = 0.f;
  for (int t = 0; t < 4; ++t) s += w2[idx * 4 + t];
  wsum[idx] = 0.25f * s;
}

// ------------- K1: 7x7 P4 lifting conv via split-f16 MFMA + BN block partials -------------
// Block: 16x16 pixel tile, 512 threads (8 waves). Wave w: pixel-col strips {2w, 2w+1}.
// MFMA 16x16x32_f16: D[m=j][n=pixel-row]; A = weights (global, frag-ordered, dbuf regs);
// B = x patches from LDS (1 aligned b128 per frag). acc_hh + acc_cross*(1/2048).
__global__ __launch_bounds__(512) void k_conv1(
    const float* __restrict__ xsrc,   // NHWC [B,H,W,16]
    const ushort* __restrict__ wfh,   // A-frags hi  [NKS*4*64] x 8 f16
    const ushort* __restrict__ wfl,   // A-frags lo (x2048)
    const float* __restrict__ b1,     // [16]
    float* __restrict__ y,            // [NPIX][64]
    float* __restrict__ partials)     // [1152][32]
{
  __shared__ __align__(16) ushort xs[2 * XBUFU];   // hi | lo (x2048), 34592 B
  __shared__ float red2[8][32];
  const int tid = threadIdx.x;
  const int lane = tid & 63, wid = tid >> 6;
  const int x0 = blockIdx.x * TILE, y0 = blockIdx.y * TILE;
  const int b = blockIdx.z;

  // ---- stage x tile (+halo, rows 0..22) as split f16, pixel-major ----
  for (int p = tid; p < XROWS * 22; p += 512) {
    const int lr = p / 22, lc = p - (p / 22) * 22;
    const int gy = y0 + lr - 3, gx = x0 + lc - 3;
    float4 v0, v1, v2, v3;
    if ((unsigned)gy < (unsigned)HH && (unsigned)gx < (unsigned)WW) {
      const float4* px = (const float4*)(xsrc + ((size_t)b * HWSZ + (size_t)gy * WW + gx) * 16);
      v0 = px[0]; v1 = px[1]; v2 = px[2]; v3 = px[3];
    } else {
      v0 = v1 = v2 = v3 = make_float4(0.f, 0.f, 0.f, 0.f);
    }
    const float xv[16] = {v0.x, v0.y, v0.z, v0.w, v1.x, v1.y, v1.z, v1.w,
                          v2.x, v2.y, v2.z, v2.w, v3.x, v3.y, v3.z, v3.w};
    PackU h0, h1, l0, l1;
#pragma unroll
    for (int c = 0; c < 8; ++c) split2048(xv[c], h0.u[c], l0.u[c]);
#pragma unroll
    for (int c = 0; c < 8; ++c) split2048(xv[8 + c], h1.u[c], l1.u[c]);
    const int ub = lr * RSU + lc * 16;
    *(uint4*)&xs[ub] = h0.v;
    *(uint4*)&xs[ub + 8] = h1.v;
    *(uint4*)&xs[XBUFU + ub] = l0.v;
    *(uint4*)&xs[XBUFU + ub + 8] = l1.v;
  }
  __syncthreads();   // the ONLY barrier before epilogue: LDS read-only afterwards

  // ---- per-lane geometry ----
  const int n = lane & 15;            // D col = pixel row in tile
  const int q = lane >> 4;            // D row group
  const int h = q & 1;                // ci half for B reads
  const int c0 = 2 * wid;             // strip 0 col (strip 1 = c0+1)
  const int bU0 = n * RSU + c0 * 16 + h * 8;   // ushort idx base, strip 0
  const int bU1 = bU0 + 16;

  const f16x8* __restrict__ WAh = (const f16x8*)wfh;
  const f16x8* __restrict__ WAl = (const f16x8*)wfl;

  float bias[4];
#pragma unroll
  for (int mt = 0; mt < 4; ++mt) bias[mt] = b1[mt * 4 + q];

  f32x4 accH[2][4], accC[2][4];
#pragma unroll
  for (int st = 0; st < 2; ++st)
#pragma unroll
    for (int mt = 0; mt < 4; ++mt) {
      const float bv = bias[mt];
      accH[st][mt] = (f32x4){bv, bv, bv, bv};
      accC[st][mt] = (f32x4){0.f, 0.f, 0.f, 0.f};
    }

  f16x8 Ah[2][4], Al[2][4];
#pragma unroll
  for (int mt = 0; mt < 4; ++mt) {
    Ah[0][mt] = WAh[mt * 64 + lane];
    Al[0][mt] = WAl[mt * 64 + lane];
  }

#pragma unroll
  for (int s = 0; s < NKS; ++s) {
    const int cb = s & 1, nb = cb ^ 1;
    if (s < NKS - 1) {
#pragma unroll
      for (int mt = 0; mt < 4; ++mt) {
        const int f = ((s + 1) * 4 + mt) * 64 + lane;
        Ah[nb][mt] = WAh[f];
        Al[nb][mt] = WAl[f];
      }
    }
    // B fragments: taps t0=2s (lanes<32), t1=2s+1 (lanes>=32)
    const int t0 = 2 * s, t1 = 2 * s + 1;
    const int o0 = (t0 < 49) ? (t0 / 7) * RSU + (t0 % 7) * 16 : 7 * RSU;
    const int o1 = (t1 < 49) ? (t1 / 7) * RSU + (t1 % 7) * 16 : 7 * RSU;
    const int off = (lane < 32) ? o0 : o1;
    const f16x8 bh0 = *(const f16x8*)&xs[bU0 + off];
    const f16x8 bl0 = *(const f16x8*)&xs[XBUFU + bU0 + off];
    const f16x8 bh1 = *(const f16x8*)&xs[bU1 + off];
    const f16x8 bl1 = *(const f16x8*)&xs[XBUFU + bU1 + off];

#pragma unroll
    for (int mt = 0; mt < 4; ++mt) {
      accH[0][mt] = __builtin_amdgcn_mfma_f32_16x16x32_f16(Ah[cb][mt], bh0, accH[0][mt], 0, 0, 0);
      accC[0][mt] = __builtin_amdgcn_mfma_f32_16x16x32_f16(Ah[cb][mt], bl0, accC[0][mt], 0, 0, 0);
      accC[0][mt] = __builtin_amdgcn_mfma_f32_16x16x32_f16(Al[cb][mt], bh0, accC[0][mt], 0, 0, 0);
      accH[1][mt] = __builtin_amdgcn_mfma_f32_16x16x32_f16(Ah[cb][mt], bh1, accH[1][mt], 0, 0, 0);
      accC[1][mt] = __builtin_amdgcn_mfma_f32_16x16x32_f16(Ah[cb][mt], bl1, accC[1][mt], 0, 0, 0);
      accC[1][mt] = __builtin_amdgcn_mfma_f32_16x16x32_f16(Al[cb][mt], bh1, accC[1][mt], 0, 0, 0);
    }
  }

  // ---- epilogue: combine, store y, BN partials ----
  float sC[4] = {0.f, 0.f, 0.f, 0.f}, qC[4] = {0.f, 0.f, 0.f, 0.f};
#pragma unroll
  for (int st = 0; st < 2; ++st) {
    const size_t pix = (size_t)b * HWSZ + (size_t)(y0 + n) * WW + (x0 + c0 + st);
#pragma unroll
    for (int mt = 0; mt < 4; ++mt) {
      f32x4 res = accH[st][mt] + accC[st][mt] * 4.8828125e-4f;  // 1/2048
      *(float4*)(y + pix * 64 + mt * 16 + q * 4) =
          make_float4(res[0], res[1], res[2], res[3]);
#pragma unroll
      for (int r = 0; r < 4; ++r) { sC[mt] += res[r]; qC[mt] += res[r] * res[r]; }
    }
  }
#pragma unroll
  for (int mt = 0; mt < 4; ++mt) {
    float s = sC[mt], s2 = qC[mt];
#pragma unroll
    for (int off = 1; off <= 8; off <<= 1) {
      s += __shfl_xor(s, off); s2 += __shfl_xor(s2, off);
    }
    if (n == 0) {   // lane q*16: channel c = mt*4 + q
      red2[wid][(mt * 4 + q) * 2] = s;
      red2[wid][(mt * 4 + q) * 2 + 1] = s2;
    }
  }
  __syncthreads();
  if (tid < 32) {
    float v = 0.f;
#pragma unroll
    for (int w2i = 0; w2i < 8; ++w2i) v += red2[w2i][tid];
    const int blk = (b * gridDim.y + blockIdx.y) * gridDim.x + blockIdx.x;
    partials[(size_t)blk * 32 + tid] = v;
  }
}

// ------------- K2: reduce BN partials -> scale/shift per channel -------------
__global__ __launch_bounds__(256) void k_bnstats(
    const float* __restrict__ partials,  // [1152][32]
    const float* __restrict__ gamma, const float* __restrict__ beta,
    float* __restrict__ stats)           // [16][2] = scale, shift
{
  const int c = blockIdx.x;      // 16 blocks
  const int tid = threadIdx.x;   // 256
  float s = 0.f, s2 = 0.f;
  for (int i = tid; i < 1152; i += 256) {
    s  += partials[(size_t)i * 32 + 2 * c];
    s2 += partials[(size_t)i * 32 + 2 * c + 1];
  }
  __shared__ float rs[256], rs2[256];
  rs[tid] = s; rs2[tid] = s2;
  __syncthreads();
  for (int off = 128; off > 0; off >>= 1) {
    if (tid < off) { rs[tid] += rs[tid + off]; rs2[tid] += rs2[tid + off]; }
    __syncthreads();
  }
  if (tid == 0) {
    const float N = (float)BB * 4.f * HH * WW;  // 1,179,648
    const float mu = rs[0] / N;
    const float var = rs2[0] / N - mu * mu;
    const float rstd = rsqrtf(var + 1e-5f);
    const float sc = gamma[c] * rstd;
    stats[2 * c]     = sc;
    stats[2 * c + 1] = beta[c] - mu * sc;
  }
}

// ------------- K3: BN+relu+orientation-sum+1x1 conv+mask+state update -------------
__global__ __launch_bounds__(256) void k_update(
    const float* __restrict__ xsrc,  // NHWC state (d_in step0, else d_out)
    const float* __restrict__ y,     // [NPIX][64]
    const float* __restrict__ stats, // [16][2]
    const float* __restrict__ wsum,  // [16][16]
    const float* __restrict__ b2,    // [16]
    float* __restrict__ xdst,        // NHWC state out (d_out)
    uint32_t fk0, uint32_t fk1)
{
  __shared__ float sss[32];
  __shared__ float sws[256];
  __shared__ float sb2[16];
  const int tid = threadIdx.x;
  sws[tid] = wsum[tid];
  if (tid < 32) sss[tid] = stats[tid];
  if (tid < 16) sb2[tid] = b2[tid];
  __syncthreads();

  const size_t pix = (size_t)blockIdx.x * 256 + tid;  // < NPIX exactly
  const float4* yp = (const float4*)(y + pix * 64);
  float ysum[16];
#pragma unroll
  for (int c = 0; c < 16; ++c) {
    const float4 v = yp[c];
    const float sc = sss[2 * c], sh = sss[2 * c + 1];
    ysum[c] = fmaxf(fmaf(sc, v.x, sh), 0.f) + fmaxf(fmaf(sc, v.y, sh), 0.f)
            + fmaxf(fmaf(sc, v.z, sh), 0.f) + fmaxf(fmaf(sc, v.w, sh), 0.f);
  }

  // JAX partitionable threefry: bits = h0 ^ h1 of hash(fk, (0, i))
  uint32_t h0, h1;
  tf2x32(fk0, fk1, 0u, (uint32_t)pix, h0, h1);
  const uint32_t bits = h0 ^ h1;
  const float u = __uint_as_float((bits >> 9) | 0x3f800000u) - 1.0f;
  const float m = (u > 0.5f) ? 1.0f : 0.0f;

  const float4* xp = (const float4*)(xsrc + pix * 16);
  float4* op = (float4*)(xdst + pix * 16);
#pragma unroll
  for (int qq = 0; qq < 4; ++qq) {
    const float4 xv = xp[qq];
    float d[4];
#pragma unroll
    for (int jj = 0; jj < 4; ++jj) {
      const int o = 4 * qq + jj;
      float s = sb2[o];
#pragma unroll
      for (int c = 0; c < 16; ++c) s = fmaf(sws[o * 16 + c], ysum[c], s);
      d[jj] = s;
    }
    float4 r;
    r.x = xv.x + d[0] * m;
    r.y = xv.y + d[1] * m;
    r.z = xv.z + d[2] * m;
    r.w = xv.w + d[3] * m;
    if (qq == 0) r.x = xv.x;  // channel 0 clamped to original input
    op[qq] = r;
  }
}

extern "C" void kernel_launch(void* const* d_in, const int* in_sizes, int n_in,
                              void* d_out, int out_size, void* d_ws, size_t ws_size,
                              hipStream_t stream) {
  const float* x_in  = (const float*)d_in[0];
  const float* w1    = (const float*)d_in[1];
  const float* b1    = (const float*)d_in[2];
  const float* gamma = (const float*)d_in[3];
  const float* beta  = (const float*)d_in[4];
  const float* w2    = (const float*)d_in[5];
  const float* b2    = (const float*)d_in[6];
  float* out = (float*)d_out;

  // workspace carve-up: y (75.5 MB) + wfrags + small buffers
  float* ws       = (float*)d_ws;
  float* y        = ws;                              // NPIX*64 floats
  ushort* wfh     = (ushort*)(y + (size_t)NPIX * 64); // 25*4*64*8 = 51200 ushorts
  ushort* wfl     = wfh + NKS * 4 * 64 * 8;
  float* wsum     = (float*)(wfl + NKS * 4 * 64 * 8); // 102400 B offset, 16B aligned
  float* partials = wsum + 256;                      // 1152*32
  float* stats    = partials + 1152 * 32;            // 32

  k_prep_wfrag<<<NKS, 256, 0, stream>>>(w1, wfh, wfl);
  k_prep_w2<<<1, 256, 0, stream>>>(w2, wsum);

  for (int s = 0; s < NSTEP; ++s) {
    const float* xsrc = (s == 0) ? x_in : out;
    k_conv1<<<dim3(WW / TILE, HH / TILE, BB), 512, 0, stream>>>(xsrc, wfh, wfl, b1, y, partials);
    k_bnstats<<<16, 256, 0, stream>>>(partials, gamma, beta, stats);
    uint32_t fk0, fk1;
    tf2x32(0u, 42u, 0u, (uint32_t)s, fk0, fk1);
    k_update<<<NPIX / 256, 256, 0, stream>>>(xsrc, y, stats, wsum, b2, out, fk0, fk1);
  }
}

// Round 5
// 1235.815 us; speedup vs baseline: 9.0245x; 1.4479x over previous
//
#include <hip/hip_runtime.h>
#include <stdint.h>

// Problem constants (setup_inputs is fixed)
#define HH 192
#define WW 192
#define BB 8
#define NSTEP 10
#define HWSZ (HH*WW)    // 36864
#define NPIX (BB*HWSZ)  // 294912
#define TILE 16

// x LDS tile geometry (f16, pixel-major): row stride 376 ushorts = 752 B = 47*16B
#define XROWS 23
#define RSU   376                 // ushorts per row
#define XBUFU (XROWS*RSU)         // 8648 ushorts per buffer (hi); lo at +XBUFU
#define NKS   25                  // K-steps: 50 taps (49 + 1 zero-pad) * 16 ci / 32

typedef _Float16 f16x8 __attribute__((ext_vector_type(8)));
typedef float    f32x4 __attribute__((ext_vector_type(4)));

union PackU { ushort u[8]; uint4 v; };

// ---------------- Threefry-2x32 (exact JAX semantics) ----------------
__host__ __device__ inline void tf2x32(uint32_t k0, uint32_t k1,
                                       uint32_t x0, uint32_t x1,
                                       uint32_t &o0, uint32_t &o1) {
  const uint32_t k2 = k0 ^ k1 ^ 0x1BD11BDAu;
  x0 += k0; x1 += k1;
#define TFR(r) { x0 += x1; x1 = (x1 << (r)) | (x1 >> (32 - (r))); x1 ^= x0; }
  TFR(13) TFR(15) TFR(26) TFR(6)
  x0 += k1; x1 += k2 + 1u;
  TFR(17) TFR(29) TFR(16) TFR(24)
  x0 += k2; x1 += k0 + 2u;
  TFR(13) TFR(15) TFR(26) TFR(6)
  x0 += k0; x1 += k1 + 3u;
  TFR(17) TFR(29) TFR(16) TFR(24)
  x0 += k1; x1 += k2 + 4u;
  TFR(13) TFR(15) TFR(26) TFR(6)
  x0 += k2; x1 += k0 + 5u;
#undef TFR
  o0 = x0; o1 = x1;
}

__device__ inline void split2048(float v, ushort &h, ushort &l) {
  _Float16 hi = (_Float16)v;
  float r = (v - (float)hi) * 2048.0f;   // scale lo into normal f16 range
  _Float16 lo = (_Float16)r;
  h = __builtin_bit_cast(ushort, hi);
  l = __builtin_bit_cast(ushort, lo);
}

// ------------- K0a: weights -> A-fragment order, f16 hi/lo (lo scaled x2048) -------------
__global__ void k_prep_wfrag(const float* __restrict__ w1,
                             ushort* __restrict__ wfh, ushort* __restrict__ wfl) {
  int idx = blockIdx.x * 256 + threadIdx.x;   // 6400 total
  if (idx >= NKS * 4 * 64) return;
  const int lane = idx & 63;
  const int sm = idx >> 6;            // s*4 + mt
  const int s = sm >> 2, mt = sm & 3;
  const int m = lane & 15, g = lane >> 4;
  const int j = mt * 16 + m, co = j >> 2, r = j & 3;
  const int t = 2 * s + (g >> 1);
  PackU ph, pl;
#pragma unroll
  for (int e = 0; e < 8; ++e) {
    const int ci = 8 * (g & 1) + e;
    float wv = 0.f;
    if (t < 49) {
      const int ky = t / 7, kx = t - (t / 7) * 7;
      int a = ky, b = kx;
      for (int i = 0; i < r; ++i) { int na = b, nb = 6 - a; a = na; b = nb; }
      wv = w1[((co * 16 + ci) * 7 + a) * 7 + b];
    }
    split2048(wv, ph.u[e], pl.u[e]);
  }
  ((uint4*)wfh)[sm * 64 + lane] = ph.v;
  ((uint4*)wfl)[sm * 64 + lane] = pl.v;
}

// ------------- K0b: wsum[o][ci] = 0.25 * sum_t w2[o,ci,t] -------------
__global__ void k_prep_w2(const float* __restrict__ w2, float* __restrict__ wsum) {
  int idx = threadIdx.x;  // 256 = o*16 + ci
  float s = 0.f;
  for (int t = 0; t < 4; ++t) s += w2[idx * 4 + t];
  wsum[idx] = 0.25f * s;
}

// ------------- K1: 7x7 P4 lifting conv via split-f16 MFMA + BN block partials -------------
// Software-pipelined: iteration s issues A(s+1) global loads + B(s+1) ds_reads,
// then (sched_barrier-pinned) runs the 24-MFMA cluster on registers of step s.
__global__ __launch_bounds__(512) void k_conv1(
    const float* __restrict__ xsrc,   // NHWC [B,H,W,16]
    const ushort* __restrict__ wfh,   // A-frags hi  [NKS*4*64] x 8 f16
    const ushort* __restrict__ wfl,   // A-frags lo (x2048)
    const float* __restrict__ b1,     // [16]
    float* __restrict__ y,            // [NPIX][64]
    float* __restrict__ partials)     // [1152][32]
{
  __shared__ __align__(16) ushort xs[2 * XBUFU];   // hi | lo (x2048), 34592 B
  __shared__ float red2[8][32];
  const int tid = threadIdx.x;
  const int lane = tid & 63, wid = tid >> 6;
  const int x0 = blockIdx.x * TILE, y0 = blockIdx.y * TILE;
  const int b = blockIdx.z;

  // ---- stage x tile (+halo) as split f16, pixel-major ----
  for (int p = tid; p < XROWS * 22; p += 512) {
    const int lr = p / 22, lc = p - (p / 22) * 22;
    const int gy = y0 + lr - 3, gx = x0 + lc - 3;
    float4 v0, v1, v2, v3;
    if ((unsigned)gy < (unsigned)HH && (unsigned)gx < (unsigned)WW) {
      const float4* px = (const float4*)(xsrc + ((size_t)b * HWSZ + (size_t)gy * WW + gx) * 16);
      v0 = px[0]; v1 = px[1]; v2 = px[2]; v3 = px[3];
    } else {
      v0 = v1 = v2 = v3 = make_float4(0.f, 0.f, 0.f, 0.f);
    }
    const float xv[16] = {v0.x, v0.y, v0.z, v0.w, v1.x, v1.y, v1.z, v1.w,
                          v2.x, v2.y, v2.z, v2.w, v3.x, v3.y, v3.z, v3.w};
    PackU h0, h1, l0, l1;
#pragma unroll
    for (int c = 0; c < 8; ++c) split2048(xv[c], h0.u[c], l0.u[c]);
#pragma unroll
    for (int c = 0; c < 8; ++c) split2048(xv[8 + c], h1.u[c], l1.u[c]);
    const int ub = lr * RSU + lc * 16;
    *(uint4*)&xs[ub] = h0.v;
    *(uint4*)&xs[ub + 8] = h1.v;
    *(uint4*)&xs[XBUFU + ub] = l0.v;
    *(uint4*)&xs[XBUFU + ub + 8] = l1.v;
  }
  __syncthreads();   // the ONLY barrier before epilogue: LDS read-only afterwards

  // ---- per-lane geometry ----
  const int n = lane & 15;            // D col = pixel row in tile
  const int q = lane >> 4;            // D row group
  const int h = q & 1;                // ci half for B reads
  const int c0 = 2 * wid;             // strip 0 col (strip 1 = c0+1)
  const int bU0 = n * RSU + c0 * 16 + h * 8;   // ushort idx base, strip 0
  const int bU1 = bU0 + 16;

  const f16x8* __restrict__ WAh = (const f16x8*)wfh;
  const f16x8* __restrict__ WAl = (const f16x8*)wfl;

  float bias[4];
#pragma unroll
  for (int mt = 0; mt < 4; ++mt) bias[mt] = b1[mt * 4 + q];

  f32x4 accH[2][4], accC[2][4];
#pragma unroll
  for (int st = 0; st < 2; ++st)
#pragma unroll
    for (int mt = 0; mt < 4; ++mt) {
      const float bv = bias[mt];
      accH[st][mt] = (f32x4){bv, bv, bv, bv};
      accC[st][mt] = (f32x4){0.f, 0.f, 0.f, 0.f};
    }

  f16x8 Ah[2][4], Al[2][4];
  f16x8 Bh0[2], Bl0[2], Bh1[2], Bl1[2];

  // prologue: step-0 fragments
#pragma unroll
  for (int mt = 0; mt < 4; ++mt) {
    Ah[0][mt] = WAh[mt * 64 + lane];
    Al[0][mt] = WAl[mt * 64 + lane];
  }
  {
    const int off = (lane < 32) ? 0 : 16;   // s=0: taps 0 (o=0), 1 (o=16)
    Bh0[0] = *(const f16x8*)&xs[bU0 + off];
    Bl0[0] = *(const f16x8*)&xs[XBUFU + bU0 + off];
    Bh1[0] = *(const f16x8*)&xs[bU1 + off];
    Bl1[0] = *(const f16x8*)&xs[XBUFU + bU1 + off];
  }

#pragma unroll
  for (int s = 0; s < NKS; ++s) {
    const int cb = s & 1, nb = cb ^ 1;
    if (s < NKS - 1) {
      // ---- prefetch step s+1: A from global (L2), B from LDS ----
#pragma unroll
      for (int mt = 0; mt < 4; ++mt) {
        const int f = ((s + 1) * 4 + mt) * 64 + lane;
        Ah[nb][mt] = WAh[f];
        Al[nb][mt] = WAl[f];
      }
      const int t0 = 2 * (s + 1), t1 = t0 + 1;
      const int o0 = (t0 / 7) * RSU + (t0 % 7) * 16;
      const int o1 = (t1 < 49) ? (t1 / 7) * RSU + (t1 % 7) * 16 : 0;  // pad tap: x*0-weights
      const int off = (lane < 32) ? o0 : o1;
      Bh0[nb] = *(const f16x8*)&xs[bU0 + off];
      Bl0[nb] = *(const f16x8*)&xs[XBUFU + bU0 + off];
      Bh1[nb] = *(const f16x8*)&xs[bU1 + off];
      Bl1[nb] = *(const f16x8*)&xs[XBUFU + bU1 + off];
    }
    __builtin_amdgcn_sched_barrier(0);   // pin prefetch issue before MFMA cluster
    __builtin_amdgcn_s_setprio(1);
#pragma unroll
    for (int mt = 0; mt < 4; ++mt) {
      accH[0][mt] = __builtin_amdgcn_mfma_f32_16x16x32_f16(Ah[cb][mt], Bh0[cb], accH[0][mt], 0, 0, 0);
      accH[1][mt] = __builtin_amdgcn_mfma_f32_16x16x32_f16(Ah[cb][mt], Bh1[cb], accH[1][mt], 0, 0, 0);
      accC[0][mt] = __builtin_amdgcn_mfma_f32_16x16x32_f16(Ah[cb][mt], Bl0[cb], accC[0][mt], 0, 0, 0);
      accC[0][mt] = __builtin_amdgcn_mfma_f32_16x16x32_f16(Al[cb][mt], Bh0[cb], accC[0][mt], 0, 0, 0);
      accC[1][mt] = __builtin_amdgcn_mfma_f32_16x16x32_f16(Ah[cb][mt], Bl1[cb], accC[1][mt], 0, 0, 0);
      accC[1][mt] = __builtin_amdgcn_mfma_f32_16x16x32_f16(Al[cb][mt], Bh1[cb], accC[1][mt], 0, 0, 0);
    }
    __builtin_amdgcn_s_setprio(0);
    __builtin_amdgcn_sched_barrier(0);
  }

  // ---- epilogue: combine, store y, BN partials ----
  float sC[4] = {0.f, 0.f, 0.f, 0.f}, qC[4] = {0.f, 0.f, 0.f, 0.f};
#pragma unroll
  for (int st = 0; st < 2; ++st) {
    const size_t pix = (size_t)b * HWSZ + (size_t)(y0 + n) * WW + (x0 + c0 + st);
#pragma unroll
    for (int mt = 0; mt < 4; ++mt) {
      f32x4 res = accH[st][mt] + accC[st][mt] * 4.8828125e-4f;  // 1/2048
      *(float4*)(y + pix * 64 + mt * 16 + q * 4) =
          make_float4(res[0], res[1], res[2], res[3]);
#pragma unroll
      for (int r = 0; r < 4; ++r) { sC[mt] += res[r]; qC[mt] += res[r] * res[r]; }
    }
  }
#pragma unroll
  for (int mt = 0; mt < 4; ++mt) {
    float s = sC[mt], s2 = qC[mt];
#pragma unroll
    for (int off = 1; off <= 8; off <<= 1) {
      s += __shfl_xor(s, off); s2 += __shfl_xor(s2, off);
    }
    if (n == 0) {   // lane q*16: channel c = mt*4 + q
      red2[wid][(mt * 4 + q) * 2] = s;
      red2[wid][(mt * 4 + q) * 2 + 1] = s2;
    }
  }
  __syncthreads();
  if (tid < 32) {
    float v = 0.f;
#pragma unroll
    for (int w2i = 0; w2i < 8; ++w2i) v += red2[w2i][tid];
    const int blk = (b * gridDim.y + blockIdx.y) * gridDim.x + blockIdx.x;
    partials[(size_t)blk * 32 + tid] = v;
  }
}

// ------------- K2: reduce BN partials -> scale/shift per channel -------------
__global__ __launch_bounds__(256) void k_bnstats(
    const float* __restrict__ partials,  // [1152][32]
    const float* __restrict__ gamma, const float* __restrict__ beta,
    float* __restrict__ stats)           // [16][2] = scale, shift
{
  const int c = blockIdx.x;      // 16 blocks
  const int tid = threadIdx.x;   // 256
  float s = 0.f, s2 = 0.f;
  for (int i = tid; i < 1152; i += 256) {
    s  += partials[(size_t)i * 32 + 2 * c];
    s2 += partials[(size_t)i * 32 + 2 * c + 1];
  }
  __shared__ float rs[256], rs2[256];
  rs[tid] = s; rs2[tid] = s2;
  __syncthreads();
  for (int off = 128; off > 0; off >>= 1) {
    if (tid < off) { rs[tid] += rs[tid + off]; rs2[tid] += rs2[tid + off]; }
    __syncthreads();
  }
  if (tid == 0) {
    const float N = (float)BB * 4.f * HH * WW;  // 1,179,648
    const float mu = rs[0] / N;
    const float var = rs2[0] / N - mu * mu;
    const float rstd = rsqrtf(var + 1e-5f);
    const float sc = gamma[c] * rstd;
    stats[2 * c]     = sc;
    stats[2 * c + 1] = beta[c] - mu * sc;
  }
}

// ------------- K3: BN+relu+orientation-sum+1x1 conv+mask+state update -------------
__global__ __launch_bounds__(256) void k_update(
    const float* __restrict__ xsrc,  // NHWC state (d_in step0, else d_out)
    const float* __restrict__ y,     // [NPIX][64]
    const float* __restrict__ stats, // [16][2]
    const float* __restrict__ wsum,  // [16][16]
    const float* __restrict__ b2,    // [16]
    float* __restrict__ xdst,        // NHWC state out (d_out)
    uint32_t fk0, uint32_t fk1)
{
  __shared__ float sss[32];
  __shared__ float sws[256];
  __shared__ float sb2[16];
  const int tid = threadIdx.x;
  sws[tid] = wsum[tid];
  if (tid < 32) sss[tid] = stats[tid];
  if (tid < 16) sb2[tid] = b2[tid];
  __syncthreads();

  const size_t pix = (size_t)blockIdx.x * 256 + tid;  // < NPIX exactly
  const float4* yp = (const float4*)(y + pix * 64);
  float ysum[16];
#pragma unroll
  for (int c = 0; c < 16; ++c) {
    const float4 v = yp[c];
    const float sc = sss[2 * c], sh = sss[2 * c + 1];
    ysum[c] = fmaxf(fmaf(sc, v.x, sh), 0.f) + fmaxf(fmaf(sc, v.y, sh), 0.f)
            + fmaxf(fmaf(sc, v.z, sh), 0.f) + fmaxf(fmaf(sc, v.w, sh), 0.f);
  }

  // JAX partitionable threefry: bits = h0 ^ h1 of hash(fk, (0, i))
  uint32_t h0, h1;
  tf2x32(fk0, fk1, 0u, (uint32_t)pix, h0, h1);
  const uint32_t bits = h0 ^ h1;
  const float u = __uint_as_float((bits >> 9) | 0x3f800000u) - 1.0f;
  const float m = (u > 0.5f) ? 1.0f : 0.0f;

  const float4* xp = (const float4*)(xsrc + pix * 16);
  float4* op = (float4*)(xdst + pix * 16);
#pragma unroll
  for (int qq = 0; qq < 4; ++qq) {
    const float4 xv = xp[qq];
    float d[4];
#pragma unroll
    for (int jj = 0; jj < 4; ++jj) {
      const int o = 4 * qq + jj;
      float s = sb2[o];
#pragma unroll
      for (int c = 0; c < 16; ++c) s = fmaf(sws[o * 16 + c], ysum[c], s);
      d[jj] = s;
    }
    float4 r;
    r.x = xv.x + d[0] * m;
    r.y = xv.y + d[1] * m;
    r.z = xv.z + d[2] * m;
    r.w = xv.w + d[3] * m;
    if (qq == 0) r.x = xv.x;  // channel 0 clamped to original input
    op[qq] = r;
  }
}

extern "C" void kernel_launch(void* const* d_in, const int* in_sizes, int n_in,
                              void* d_out, int out_size, void* d_ws, size_t ws_size,
                              hipStream_t stream) {
  const float* x_in  = (const float*)d_in[0];
  const float* w1    = (const float*)d_in[1];
  const float* b1    = (const float*)d_in[2];
  const float* gamma = (const float*)d_in[3];
  const float* beta  = (const float*)d_in[4];
  const float* w2    = (const float*)d_in[5];
  const float* b2    = (const float*)d_in[6];
  float* out = (float*)d_out;

  // workspace carve-up: y (75.5 MB) + wfrags + small buffers
  float* ws       = (float*)d_ws;
  float* y        = ws;                              // NPIX*64 floats
  ushort* wfh     = (ushort*)(y + (size_t)NPIX * 64); // 25*4*64*8 = 51200 ushorts
  ushort* wfl     = wfh + NKS * 4 * 64 * 8;
  float* wsum     = (float*)(wfl + NKS * 4 * 64 * 8); // 16B aligned
  float* partials = wsum + 256;                      // 1152*32
  float* stats    = partials + 1152 * 32;            // 32

  k_prep_wfrag<<<NKS, 256, 0, stream>>>(w1, wfh, wfl);
  k_prep_w2<<<1, 256, 0, stream>>>(w2, wsum);

  for (int s = 0; s < NSTEP; ++s) {
    const float* xsrc = (s == 0) ? x_in : out;
    k_conv1<<<dim3(WW / TILE, HH / TILE, BB), 512, 0, stream>>>(xsrc, wfh, wfl, b1, y, partials);
    k_bnstats<<<16, 256, 0, stream>>>(partials, gamma, beta, stats);
    uint32_t fk0, fk1;
    tf2x32(0u, 42u, 0u, (uint32_t)s, fk0, fk1);
    k_update<<<NPIX / 256, 256, 0, stream>>>(xsrc, y, stats, wsum, b2, out, fk0, fk1);
  }
}